// Round 5
// baseline (131.644 us; speedup 1.0000x reference)
//
#include <hip/hip_runtime.h>

// SqueezeSeg recurrent CRF, MI355X (gfx950). Single-kernel halo-redundant fusion
// (3 iterations in-block, shrinking regions 12x72 -> 10x68 -> 8x64 around 8x64).
// R5: 2 adjacent pixels per thread with row-register sharing (18 b128 + 18 b32
// LDS per pair vs 56 ops), paired float2 filt loads / output stores, and an
// even/odd-split LDS column layout so paired access stays lane-stride-1
// (conflict-free b128).
// g_ang == g_bi (theta=0.9 both) -> ang == bi_ang.
// compat = (1-I)*coef -> out[o] = coef*(sum_c v[c] - v[o]).

#define NCLASS 4
#define HH 64
#define WW 512
#define BB 16
#define TH 8
#define TW 64
#define UR (TH + 6)   // 14 rows : tile + 3 halo each side
#define UC (TW + 12)  // 76 cols : tile + 6 halo each side
#define UCH (UC / 2)  // 38: even/odd half width
#define PLANE (HH * WW)

// exp(-d2 / (2*0.9^2)) for d2 = 1,2,4,5
#define G1 0.53940412f
#define G2 0.29095687f
#define G4 0.08466190f
#define G5 0.04566227f

// even/odd split column swizzle: even cols -> [0,38), odd cols -> [38,76)
__device__ __forceinline__ constexpr int swz(int c) {
    return (c & 1) * UCH + (c >> 1);
}

// tap index in dz-major, da-minor order with center excluded (k-ordering of
// bilateral_filters)
__device__ __forceinline__ constexpr int tapk(int dz, int da) {
    const int idx = (dz + 1) * 5 + (da + 2);
    return idx > 7 ? idx - 1 : idx;
}

__device__ __forceinline__ float4 softmax4(float4 v) {
    const float mx = fmaxf(fmaxf(v.x, v.y), fmaxf(v.z, v.w));
    const float e0 = __expf(v.x - mx);
    const float e1 = __expf(v.y - mx);
    const float e2 = __expf(v.z - mx);
    const float e3 = __expf(v.w - mx);
    const float inv = 1.0f / (e0 + e1 + e2 + e3);
    return make_float4(e0 * inv, e1 * inv, e2 * inv, e3 * inv);
}

// MR/MC: halo margin (rows/cols) of the region this step computes.
template <int MR, int MC, bool FINAL>
__device__ __forceinline__ void crf_step(
    float4 (*__restrict__ u_lds)[UC], const float (*__restrict__ m_lds)[UC],
    const float* __restrict__ filt, float* __restrict__ dst,
    int b, int h0, int w0, int tid)
{
    constexpr int RH  = TH + 2 * MR;
    constexpr int RW  = TW + 2 * MC;
    constexpr int NPX = RH * RW;
    constexpr int NS  = (NPX + 511) / 512;   // pixel-pairs per thread
    const float GW[14] = {G5,G2,G1,G2,G5, G4,G1,G1,G4, G5,G2,G1,G2,G5};

    float4 xn[NS][2];

#pragma unroll
    for (int j = 0; j < NS; ++j) {
        xn[j][0] = make_float4(0.f, 0.f, 0.f, 0.f);
        xn[j][1] = make_float4(0.f, 0.f, 0.f, 0.f);
        const int s = 2 * (tid + 256 * j);
        if (s < NPX) {
            const int lr = s / RW;
            const int lc = s - lr * RW;          // even (RW even, s even)
            const int gh = h0 + lr - MR;
            const int gw = w0 + lc - MC;         // even
            const int ur = lr + (3 - MR);
            const int uc = lc + (6 - MC);        // even
            const bool rowIn = (gh >= 0) && (gh < HH);
            const bool in0 = rowIn && (gw >= 0) && (gw < WW);
            const bool in1 = rowIn && (gw + 1 >= 0) && (gw + 1 < WW);

            // ---- filt pair loads (iteration k-planes, L2/L3-resident) ----
            float F0[14], F1[14];
            const float* fp = filt + ((size_t)b * 14 * HH + gh) * WW + gw;
            if (in0 && in1) {
#pragma unroll
                for (int k = 0; k < 14; ++k) {
                    const float2 f2 = *(const float2*)(fp + (size_t)k * PLANE);
                    F0[k] = f2.x; F1[k] = f2.y;
                }
            } else {
#pragma unroll
                for (int k = 0; k < 14; ++k) {
                    F0[k] = in0 ? fp[(size_t)k * PLANE] : 0.f;
                    F1[k] = in1 ? fp[(size_t)k * PLANE + 1] : 0.f;
                }
            }

            // ---- 14-tap stencil over 3 register-cached rows ----
            float4 A0 = make_float4(0.f,0.f,0.f,0.f), C0 = A0, A1 = A0, C1 = A0;
            float4 cen0, cen1;
            float  mc0 = 0.f, mc1 = 0.f;
#pragma unroll
            for (int dz = -1; dz <= 1; ++dz) {
                const int rr = ur + dz;
                float4 U[6];
                float  M[6];
#pragma unroll
                for (int t = 0; t < 6; ++t) {
                    const int col = uc - 2 + t;
                    U[t] = u_lds[rr][swz(col)];
                    M[t] = m_lds[rr][swz(col)];
                }
                if (dz == 0) {           // capture centers from the mid row
                    cen0 = U[2]; cen1 = U[3];
                    mc0  = M[2]; mc1  = M[3];
                }
#pragma unroll
                for (int da = -2; da <= 2; ++da) {
                    if (dz == 0 && da == 0) continue;
                    const int   k   = tapk(dz, da);
                    const float gk  = GW[k];
                    const float fm0 = F0[k] * M[da + 2];
                    const float fm1 = F1[k] * M[da + 3];
                    const float4 u0 = U[da + 2];
                    const float4 u1 = U[da + 3];
                    A0.x = fmaf(gk,  u0.x, A0.x);  C0.x = fmaf(fm0, u0.x, C0.x);
                    A0.y = fmaf(gk,  u0.y, A0.y);  C0.y = fmaf(fm0, u0.y, C0.y);
                    A0.z = fmaf(gk,  u0.z, A0.z);  C0.z = fmaf(fm0, u0.z, C0.z);
                    A0.w = fmaf(gk,  u0.w, A0.w);  C0.w = fmaf(fm0, u0.w, C0.w);
                    A1.x = fmaf(gk,  u1.x, A1.x);  C1.x = fmaf(fm1, u1.x, C1.x);
                    A1.y = fmaf(gk,  u1.y, A1.y);  C1.y = fmaf(fm1, u1.y, C1.y);
                    A1.z = fmaf(gk,  u1.z, A1.z);  C1.z = fmaf(fm1, u1.z, C1.z);
                    A1.w = fmaf(gk,  u1.w, A1.w);  C1.w = fmaf(fm1, u1.w, C1.w);
                }
            }

            // ---- compat epilogue ----
            const float b0x = C0.x * mc0 * A0.x;
            const float b0y = C0.y * mc0 * A0.y;
            const float b0z = C0.z * mc0 * A0.z;
            const float b0w = C0.w * mc0 * A0.w;
            const float b1x = C1.x * mc1 * A1.x;
            const float b1y = C1.y * mc1 * A1.y;
            const float b1z = C1.z * mc1 * A1.z;
            const float b1w = C1.w * mc1 * A1.w;
            const float sa0 = A0.x + A0.y + A0.z + A0.w;
            const float sb0 = b0x + b0y + b0z + b0w;
            const float sa1 = A1.x + A1.y + A1.z + A1.w;
            const float sb1 = b1x + b1y + b1z + b1w;
            float4 r0, r1;
            r0.x = cen0.x + 0.02f * (sa0 - A0.x) + 0.1f * (sb0 - b0x);
            r0.y = cen0.y + 0.02f * (sa0 - A0.y) + 0.1f * (sb0 - b0y);
            r0.z = cen0.z + 0.02f * (sa0 - A0.z) + 0.1f * (sb0 - b0z);
            r0.w = cen0.w + 0.02f * (sa0 - A0.w) + 0.1f * (sb0 - b0w);
            r1.x = cen1.x + 0.02f * (sa1 - A1.x) + 0.1f * (sb1 - b1x);
            r1.y = cen1.y + 0.02f * (sa1 - A1.y) + 0.1f * (sb1 - b1y);
            r1.z = cen1.z + 0.02f * (sa1 - A1.z) + 0.1f * (sb1 - b1z);
            r1.w = cen1.w + 0.02f * (sa1 - A1.w) + 0.1f * (sb1 - b1w);

            if (FINAL) {
                float* o = dst + ((size_t)b * NCLASS * HH + gh) * WW + gw;
                if (in0 && in1) {
                    *(float2*)(o)             = make_float2(r0.x, r1.x);
                    *(float2*)(o +     PLANE) = make_float2(r0.y, r1.y);
                    *(float2*)(o + 2 * PLANE) = make_float2(r0.z, r1.z);
                    *(float2*)(o + 3 * PLANE) = make_float2(r0.w, r1.w);
                } else {
                    if (in0) {
                        o[0] = r0.x; o[PLANE] = r0.y;
                        o[2 * PLANE] = r0.z; o[3 * PLANE] = r0.w;
                    }
                    if (in1) {
                        o[1] = r1.x; o[PLANE + 1] = r1.y;
                        o[2 * PLANE + 1] = r1.z; o[3 * PLANE + 1] = r1.w;
                    }
                }
            } else {
                // softmax in registers -> next iteration's unary (zero if OOB)
                if (in0) xn[j][0] = softmax4(r0);
                if (in1) xn[j][1] = softmax4(r1);
            }
        }
    }

    if (!FINAL) {
        __syncthreads();   // all reads of u_t done before overwrite
#pragma unroll
        for (int j = 0; j < NS; ++j) {
            const int s = 2 * (tid + 256 * j);
            if (s < NPX) {
                const int lr = s / RW;
                const int lc = s - lr * RW;
                const int ur = lr + (3 - MR);
                const int uc = lc + (6 - MC);
                float4 (*uw)[UC] = (float4 (*)[UC])u_lds;
                uw[ur][swz(uc)]     = xn[j][0];
                uw[ur][swz(uc + 1)] = xn[j][1];
            }
        }
        __syncthreads();   // u_{t+1} visible before next step's reads
    }
}

__global__ __launch_bounds__(256, 4) void crf_fused(
    const float* __restrict__ xin,   // [B,4,H,W]
    const float* __restrict__ filt,  // [B,1,14,H,W]
    const float* __restrict__ mask,  // [B,1,H,W]
    float* __restrict__ xout)        // [B,4,H,W]
{
    __shared__ float4 u_lds[UR][UC];  // class-packed unary (even/odd split), 17.0 KB
    __shared__ float  m_lds[UR][UC];  // mask (even/odd split), 4.3 KB

    const int b   = blockIdx.z;
    const int h0  = blockIdx.y * TH;
    const int w0  = blockIdx.x * TW;
    const int tid = threadIdx.x;

    // ---- phase 0: softmax(x) + mask over the full 14x76 patch, paired ----
#pragma unroll
    for (int j = 0; j < 3; ++j) {
        const int s = 2 * (tid + 256 * j);
        if (s < UR * UC) {
            const int lr = s / UC;
            const int lc = s - lr * UC;          // even
            const int gh = h0 + lr - 3;
            const int gw = w0 + lc - 6;          // even
            const bool rowIn = (gh >= 0) && (gh < HH);
            const bool in0 = rowIn && (gw >= 0) && (gw < WW);
            const bool in1 = rowIn && (gw + 1 >= 0) && (gw + 1 < WW);
            float4 u0 = make_float4(0.f,0.f,0.f,0.f);
            float4 u1 = u0;
            float  m0 = 0.f, m1 = 0.f;
            if (in0 && in1) {
                const float* px = xin  + ((size_t)b * NCLASS * HH + gh) * WW + gw;
                const float* mp = mask + ((size_t)b * HH + gh) * WW + gw;
                const float2 v0 = *(const float2*)(px);
                const float2 v1 = *(const float2*)(px +     PLANE);
                const float2 v2 = *(const float2*)(px + 2 * PLANE);
                const float2 v3 = *(const float2*)(px + 3 * PLANE);
                const float2 mm = *(const float2*)(mp);
                u0 = softmax4(make_float4(v0.x, v1.x, v2.x, v3.x));
                u1 = softmax4(make_float4(v0.y, v1.y, v2.y, v3.y));
                m0 = mm.x; m1 = mm.y;
            } else {
                if (in0) {
                    const float* px = xin + ((size_t)b * NCLASS * HH + gh) * WW + gw;
                    u0 = softmax4(make_float4(px[0], px[PLANE], px[2*PLANE], px[3*PLANE]));
                    m0 = mask[((size_t)b * HH + gh) * WW + gw];
                }
                if (in1) {
                    const float* px = xin + ((size_t)b * NCLASS * HH + gh) * WW + gw + 1;
                    u1 = softmax4(make_float4(px[0], px[PLANE], px[2*PLANE], px[3*PLANE]));
                    m1 = mask[((size_t)b * HH + gh) * WW + gw + 1];
                }
            }
            u_lds[lr][swz(lc)]     = u0;
            u_lds[lr][swz(lc + 1)] = u1;
            m_lds[lr][swz(lc)]     = m0;
            m_lds[lr][swz(lc + 1)] = m1;
        }
    }
    __syncthreads();

    crf_step<2, 4, false>(u_lds, m_lds, filt, xout, b, h0, w0, tid);
    crf_step<1, 2, false>(u_lds, m_lds, filt, xout, b, h0, w0, tid);
    crf_step<0, 0, true >(u_lds, m_lds, filt, xout, b, h0, w0, tid);
}

extern "C" void kernel_launch(void* const* d_in, const int* in_sizes, int n_in,
                              void* d_out, int out_size, void* d_ws, size_t ws_size,
                              hipStream_t stream) {
    const float* x    = (const float*)d_in[0];  // [16,4,64,512]
    const float* filt = (const float*)d_in[1];  // [16,1,14,64,512]
    const float* msk  = (const float*)d_in[2];  // [16,1,64,512]
    float* out = (float*)d_out;
    (void)d_ws; (void)ws_size;

    dim3 grid(WW / TW, HH / TH, BB);   // (8, 8, 16) = 1024 blocks = 4/CU
    dim3 block(256);
    crf_fused<<<grid, block, 0, stream>>>(x, filt, msk, out);
}

// Round 6
// 110.252 us; speedup vs baseline: 1.1940x; 1.1940x over previous
//
#include <hip/hip_runtime.h>

// SqueezeSeg recurrent CRF, MI355X (gfx950). Single-kernel halo-redundant fusion
// (3 iterations in-block, shrinking patch regions rows/cols:
//  [1..12]x[2..73] -> [2..11]x[4..71] -> [3..10]x[6..69] of a 14x76 patch).
// R6: vertical 4-row strips per thread -> 6-row x 5-col LDS window read once
// per strip (7.5 b128 + 7.5 b32 per pixel vs R4's 14+14); separable Gaussian
// (GW = gz (x) ga) row-sums shared across the 3 stencil rows; double-buffered
// class-packed u in LDS (no result-holding registers, 1 barrier per step).
// Lanes map to consecutive columns -> stride-1 LDS, no conflicts.
// g_ang == g_bi (theta=0.9 both) -> ang == bi_ang.
// compat = (1-I)*coef -> out[o] = coef*(sum_c v[c] - v[o]).

#define NCLASS 4
#define HH 64
#define WW 512
#define BB 16
#define TH 8
#define TW 64
#define UR 14         // patch rows  (tile 8 + 3 halo each side)
#define UC 76         // patch cols  (tile 64 + 6 halo each side)
#define PLANE (HH * WW)

// Gaussian: exp(-d2/(2*0.9^2)); separable gz=[G1,1,G1], ga=[G4,G1,1,G1,G4]
#define G1 0.53940412f
#define G4 0.08466190f

// tap index, dz-major da-minor, center excluded (bilateral_filters k-order)
__device__ __forceinline__ constexpr int tapk(int dz, int da) {
    const int idx = (dz + 1) * 5 + (da + 2);
    return idx > 7 ? idx - 1 : idx;
}

__device__ __forceinline__ float4 softmax4(float4 v) {
    const float mx = fmaxf(fmaxf(v.x, v.y), fmaxf(v.z, v.w));
    const float e0 = __expf(v.x - mx);
    const float e1 = __expf(v.y - mx);
    const float e2 = __expf(v.z - mx);
    const float e3 = __expf(v.w - mx);
    const float inv = 1.0f / (e0 + e1 + e2 + e3);
    return make_float4(e0 * inv, e1 * inv, e2 * inv, e3 * inv);
}

// Computes patch rows [PT0..PT1] x cols [PC0..PC1] from u_src (+mask),
// writing softmaxed result to u_dst (or final result to global out).
template <int PT0, int PT1, int PC0, int PC1, bool FINAL>
__device__ __forceinline__ void crf_step(
    const float4 (*__restrict__ u_src)[UC],
    float4 (*__restrict__ u_dst)[UC],
    const float (*__restrict__ m_lds)[UC],
    const float* __restrict__ filt,
    float* __restrict__ out,
    int b, int h0, int w0, int tid)
{
    constexpr int RH    = PT1 - PT0 + 1;
    constexpr int RW    = PC1 - PC0 + 1;
    constexpr int QR    = (RH + 3) / 4;
    constexpr int SLOTS = QR * RW;
    static_assert(SLOTS <= 256, "one pass only");

    if (tid < SLOTS) {
        const int qr    = tid / RW;
        const int c     = tid - qr * RW;
        const int pcol  = PC0 + c;
        const int prow0 = PT0 + qr * 4;
        const int gw    = w0 + pcol - 6;
        const bool colIn = (gw >= 0) && (gw < WW);

        bool valid[4];
        int  ghr[4];
#pragma unroll
        for (int i = 0; i < 4; ++i) {
            const int pr = prow0 + i;
            const int gh = h0 + pr - 3;
            ghr[i]   = gh;
            valid[i] = (pr <= PT1) && colIn && (gh >= 0) && (gh < HH);
        }

        float4 A[4], C[4], cen[4];
        float  mcen[4];
#pragma unroll
        for (int i = 0; i < 4; ++i) {
            A[i] = make_float4(0.f, 0.f, 0.f, 0.f);
            C[i] = A[i]; cen[i] = A[i]; mcen[i] = 0.f;
        }

        const float* fbase = filt + (size_t)b * 14 * PLANE;

#pragma unroll
        for (int ir = 0; ir < 6; ++ir) {
            const int prin = prow0 - 1 + ir;       // input patch row
            if (prin <= PT1 + 1) {                 // only rows next to valid out
                float4 U[5];
                float  M[5];
#pragma unroll
                for (int t = 0; t < 5; ++t) {
                    U[t] = u_src[prin][pcol - 2 + t];
                    M[t] = m_lds[prin][pcol - 2 + t];
                }
                // separable row-sum (full 5-tap incl. center)
                float4 S;
                S.x = fmaf(G4, U[0].x + U[4].x, fmaf(G1, U[1].x + U[3].x, U[2].x));
                S.y = fmaf(G4, U[0].y + U[4].y, fmaf(G1, U[1].y + U[3].y, U[2].y));
                S.z = fmaf(G4, U[0].z + U[4].z, fmaf(G1, U[1].z + U[3].z, U[2].z));
                S.w = fmaf(G4, U[0].w + U[4].w, fmaf(G1, U[1].w + U[3].w, U[2].w));

#pragma unroll
                for (int i = 0; i < 4; ++i) {
                    const int dz = ir - 1 - i;     // input - output row
                    if (dz < -1 || dz > 1) continue;
                    const float gz = (dz == 0) ? 1.0f : G1;
                    A[i].x = fmaf(gz, S.x, A[i].x);
                    A[i].y = fmaf(gz, S.y, A[i].y);
                    A[i].z = fmaf(gz, S.z, A[i].z);
                    A[i].w = fmaf(gz, S.w, A[i].w);
                    if (dz == 0) { cen[i] = U[2]; mcen[i] = M[2]; }
                    if (valid[i]) {
                        const float* fp = fbase + (size_t)ghr[i] * WW + gw;
#pragma unroll
                        for (int da = -2; da <= 2; ++da) {
                            if (dz == 0 && da == 0) continue;
                            const int   k  = tapk(dz, da);
                            const float f  = fp[(size_t)k * PLANE];
                            const float fm = f * M[da + 2];
                            C[i].x = fmaf(fm, U[da + 2].x, C[i].x);
                            C[i].y = fmaf(fm, U[da + 2].y, C[i].y);
                            C[i].z = fmaf(fm, U[da + 2].z, C[i].z);
                            C[i].w = fmaf(fm, U[da + 2].w, C[i].w);
                        }
                    }
                }
            }
        }

        // ---- compat epilogue + write ----
#pragma unroll
        for (int i = 0; i < 4; ++i) {
            const int pr = prow0 + i;
            if (pr > PT1) continue;
            float4 r = make_float4(0.f, 0.f, 0.f, 0.f);
            if (valid[i]) {
                float4 Aa;                          // exclude center tap
                Aa.x = A[i].x - cen[i].x;
                Aa.y = A[i].y - cen[i].y;
                Aa.z = A[i].z - cen[i].z;
                Aa.w = A[i].w - cen[i].w;
                const float bx = C[i].x * mcen[i] * Aa.x;
                const float by = C[i].y * mcen[i] * Aa.y;
                const float bz = C[i].z * mcen[i] * Aa.z;
                const float bw = C[i].w * mcen[i] * Aa.w;
                const float sa = Aa.x + Aa.y + Aa.z + Aa.w;
                const float sb = bx + by + bz + bw;
                r.x = cen[i].x + 0.02f * (sa - Aa.x) + 0.1f * (sb - bx);
                r.y = cen[i].y + 0.02f * (sa - Aa.y) + 0.1f * (sb - by);
                r.z = cen[i].z + 0.02f * (sa - Aa.z) + 0.1f * (sb - bz);
                r.w = cen[i].w + 0.02f * (sa - Aa.w) + 0.1f * (sb - bw);
            }
            if (FINAL) {
                if (valid[i]) {
                    float* o = out + ((size_t)b * NCLASS * HH + ghr[i]) * WW + gw;
                    o[0]         = r.x;
                    o[PLANE]     = r.y;
                    o[2 * PLANE] = r.z;
                    o[3 * PLANE] = r.w;
                }
            } else {
                u_dst[pr][pcol] = valid[i] ? softmax4(r)
                                           : make_float4(0.f, 0.f, 0.f, 0.f);
            }
        }
    }
    if (!FINAL) __syncthreads();
}

__global__ __launch_bounds__(256, 3) void crf_fused(
    const float* __restrict__ xin,   // [B,4,H,W]
    const float* __restrict__ filt,  // [B,1,14,H,W]
    const float* __restrict__ mask,  // [B,1,H,W]
    float* __restrict__ xout)        // [B,4,H,W]
{
    __shared__ float4 uA[UR][UC];    // 17.0 KB
    __shared__ float4 uB[UR][UC];    // 17.0 KB
    __shared__ float  m_lds[UR][UC]; //  4.3 KB   -> 38.3 KB total, 4 blocks/CU

    const int b   = blockIdx.z;
    const int h0  = blockIdx.y * TH;
    const int w0  = blockIdx.x * TW;
    const int tid = threadIdx.x;

    // ---- phase 0: softmax(x) + mask over the full 14x76 patch ----
    for (int idx = tid; idx < UR * UC; idx += 256) {
        const int lr = idx / UC;
        const int lc = idx - lr * UC;
        const int gh = h0 + lr - 3;
        const int gw = w0 + lc - 6;
        float4 u = make_float4(0.f, 0.f, 0.f, 0.f);
        float  m = 0.f;
        if (gh >= 0 && gh < HH && gw >= 0 && gw < WW) {
            const float* px = xin + ((size_t)b * NCLASS * HH + gh) * WW + gw;
            u = softmax4(make_float4(px[0], px[PLANE], px[2 * PLANE], px[3 * PLANE]));
            m = mask[((size_t)b * HH + gh) * WW + gw];
        }
        uA[lr][lc]    = u;
        m_lds[lr][lc] = m;
    }
    __syncthreads();

    crf_step<1, 12, 2, 73, false>(uA, uB, m_lds, filt, xout, b, h0, w0, tid);
    crf_step<2, 11, 4, 71, false>(uB, uA, m_lds, filt, xout, b, h0, w0, tid);
    crf_step<3, 10, 6, 69, true >(uA, uB, m_lds, filt, xout, b, h0, w0, tid);
}

extern "C" void kernel_launch(void* const* d_in, const int* in_sizes, int n_in,
                              void* d_out, int out_size, void* d_ws, size_t ws_size,
                              hipStream_t stream) {
    const float* x    = (const float*)d_in[0];  // [16,4,64,512]
    const float* filt = (const float*)d_in[1];  // [16,1,14,64,512]
    const float* msk  = (const float*)d_in[2];  // [16,1,64,512]
    float* out = (float*)d_out;
    (void)d_ws; (void)ws_size;

    dim3 grid(WW / TW, HH / TH, BB);   // (8, 8, 16) = 1024 blocks = 4/CU
    dim3 block(256);
    crf_fused<<<grid, block, 0, stream>>>(x, filt, msk, out);
}

// Round 7
// 109.614 us; speedup vs baseline: 1.2010x; 1.0058x over previous
//
#include <hip/hip_runtime.h>

// SqueezeSeg recurrent CRF, MI355X (gfx950). Single-kernel halo-redundant fusion
// (3 iterations in-block, shrinking regions 12x40 -> 10x36 -> 8x32 around 8x32).
// R7: back to R4's proven 1-px/slot structure (short chains, in-place u with
// 2 barriers) but tile 8x32 -> 12.0 KB LDS, 2048 blocks = 8 blocks/CU,
// __launch_bounds__(256,6). TLP > per-thread LDS-op tricks (R6 lesson).
// g_ang == g_bi (theta=0.9 both) -> ang == bi_ang.
// compat = (1-I)*coef -> out[o] = coef*(sum_c v[c] - v[o]).

#define NCLASS 4
#define HH 64
#define WW 512
#define BB 16
#define TH 8
#define TW 32
#define UR (TH + 6)   // 14 rows : tile + 3 halo each side
#define UC (TW + 12)  // 44 cols : tile + 6 halo each side
#define PLANE (HH * WW)

// exp(-d2 / (2*0.9^2)) for d2 = 1,2,4,5
#define G1 0.53940412f
#define G2 0.29095687f
#define G4 0.08466190f
#define G5 0.04566227f

// neighbor offsets of the 3x5 kernel, center excluded, dz-major (= the
// k-ordering of bilateral_filters), relative offsets in [-1,1]x[-2,2]
#define TAPS                                                                 \
    const int   DZ[14] = {-1,-1,-1,-1,-1,  0, 0, 0, 0,  1, 1, 1, 1, 1};      \
    const int   DA[14] = {-2,-1, 0, 1, 2, -2,-1, 1, 2, -2,-1, 0, 1, 2};      \
    const float GW[14] = {G5,G2,G1,G2,G5, G4,G1,G1,G4, G5,G2,G1,G2,G5};

// MR/MC: halo margin (rows/cols) of the region this step computes.
// FINAL: write to global instead of softmax->LDS.
template <int MR, int MC, bool FINAL>
__device__ __forceinline__ void crf_step(
    float4 (*__restrict__ u_lds)[UC], const float (*__restrict__ m_lds)[UC],
    const float* __restrict__ filt, float* __restrict__ dst,
    int b, int h0, int w0, int tid)
{
    constexpr int RH = TH + 2 * MR;
    constexpr int RW = TW + 2 * MC;
    constexpr int NS = (RH * RW + 255) / 256;
    TAPS

    float4 xnew[NS];

#pragma unroll
    for (int j = 0; j < NS; ++j) {
        const int s = tid + 256 * j;
        float4 r = make_float4(0.f, 0.f, 0.f, 0.f);
        if (s < RH * RW) {
            const int lr = s / RW;
            const int lc = s - lr * RW;
            const int gh = h0 + lr - MR;
            const int gw = w0 + lc - MC;
            const int ur = lr + (3 - MR);
            const int uc = lc + (6 - MC);
            if (gh >= 0 && gh < HH && gw >= 0 && gw < WW) {
                float a0 = 0.f, a1 = 0.f, a2 = 0.f, a3 = 0.f;
                float c0 = 0.f, c1 = 0.f, c2 = 0.f, c3 = 0.f;
                const float mcen = m_lds[ur][uc];
                const float* fp = filt + ((size_t)b * 14 * HH + gh) * WW + gw;
#pragma unroll
                for (int k = 0; k < 14; ++k) {
                    const float  f  = fp[(size_t)k * PLANE];
                    const float  mn = m_lds[ur + DZ[k]][uc + DA[k]];
                    const float4 u  = u_lds[ur + DZ[k]][uc + DA[k]];
                    const float  fm = f * mn;
                    const float  gk = GW[k];
                    a0 = fmaf(gk, u.x, a0);  c0 = fmaf(fm, u.x, c0);
                    a1 = fmaf(gk, u.y, a1);  c1 = fmaf(fm, u.y, c1);
                    a2 = fmaf(gk, u.z, a2);  c2 = fmaf(fm, u.z, c2);
                    a3 = fmaf(gk, u.w, a3);  c3 = fmaf(fm, u.w, c3);
                }
                const float b0 = c0 * mcen * a0;
                const float b1 = c1 * mcen * a1;
                const float b2 = c2 * mcen * a2;
                const float b3 = c3 * mcen * a3;
                const float sa = a0 + a1 + a2 + a3;
                const float sb = b0 + b1 + b2 + b3;
                const float4 ucen = u_lds[ur][uc];
                r.x = ucen.x + 0.02f * (sa - a0) + 0.1f * (sb - b0);
                r.y = ucen.y + 0.02f * (sa - a1) + 0.1f * (sb - b1);
                r.z = ucen.z + 0.02f * (sa - a2) + 0.1f * (sb - b2);
                r.w = ucen.w + 0.02f * (sa - a3) + 0.1f * (sb - b3);
                if (!FINAL) {
                    // softmax in registers for the next iteration's unary
                    const float mx  = fmaxf(fmaxf(r.x, r.y), fmaxf(r.z, r.w));
                    const float e0  = __expf(r.x - mx);
                    const float e1  = __expf(r.y - mx);
                    const float e2  = __expf(r.z - mx);
                    const float e3  = __expf(r.w - mx);
                    const float inv = 1.0f / (e0 + e1 + e2 + e3);
                    r = make_float4(e0 * inv, e1 * inv, e2 * inv, e3 * inv);
                }
            }
            if (FINAL) {
                if (gh >= 0 && gh < HH && gw >= 0 && gw < WW) {
                    float* o = dst + ((size_t)b * NCLASS * HH + gh) * WW + gw;
                    o[0]         = r.x;
                    o[PLANE]     = r.y;
                    o[2 * PLANE] = r.z;
                    o[3 * PLANE] = r.w;
                }
            }
        }
        if (!FINAL) xnew[j] = r;
    }

    if (!FINAL) {
        __syncthreads();   // all reads of u_t done before overwrite
#pragma unroll
        for (int j = 0; j < NS; ++j) {
            const int s = tid + 256 * j;
            if (s < RH * RW) {
                const int lr = s / RW;
                const int lc = s - lr * RW;
                u_lds[lr + (3 - MR)][lc + (6 - MC)] = xnew[j];
            }
        }
        __syncthreads();   // u_{t+1} visible before next step's reads
    }
}

__global__ __launch_bounds__(256, 6) void crf_fused(
    const float* __restrict__ xin,   // [B,4,H,W]
    const float* __restrict__ filt,  // [B,1,14,H,W]
    const float* __restrict__ mask,  // [B,1,H,W]
    float* __restrict__ xout)        // [B,4,H,W]
{
    __shared__ float4 u_lds[UR][UC];  // class-packed unary, 9.6 KB
    __shared__ float  m_lds[UR][UC];  // mask, 2.4 KB   -> 12.0 KB total

    const int b   = blockIdx.z;
    const int h0  = blockIdx.y * TH;
    const int w0  = blockIdx.x * TW;
    const int tid = threadIdx.x;

    // ---- phase 0: softmax(x) + mask over the full 14x44 patch ----
    for (int idx = tid; idx < UR * UC; idx += 256) {
        const int lr = idx / UC;
        const int lc = idx - lr * UC;
        const int gh = h0 + lr - 3;
        const int gw = w0 + lc - 6;
        float4 u = make_float4(0.f, 0.f, 0.f, 0.f);
        float  m = 0.f;
        if (gh >= 0 && gh < HH && gw >= 0 && gw < WW) {
            const float* px = xin + ((size_t)b * NCLASS * HH + gh) * WW + gw;
            const float v0 = px[0];
            const float v1 = px[PLANE];
            const float v2 = px[2 * PLANE];
            const float v3 = px[3 * PLANE];
            const float mx = fmaxf(fmaxf(v0, v1), fmaxf(v2, v3));
            const float e0 = __expf(v0 - mx);
            const float e1 = __expf(v1 - mx);
            const float e2 = __expf(v2 - mx);
            const float e3 = __expf(v3 - mx);
            const float inv = 1.0f / (e0 + e1 + e2 + e3);
            u = make_float4(e0 * inv, e1 * inv, e2 * inv, e3 * inv);
            m = mask[((size_t)b * HH + gh) * WW + gw];
        }
        u_lds[lr][lc] = u;
        m_lds[lr][lc] = m;
    }
    __syncthreads();

    crf_step<2, 4, false>(u_lds, m_lds, filt, xout, b, h0, w0, tid);
    crf_step<1, 2, false>(u_lds, m_lds, filt, xout, b, h0, w0, tid);
    crf_step<0, 0, true >(u_lds, m_lds, filt, xout, b, h0, w0, tid);
}

extern "C" void kernel_launch(void* const* d_in, const int* in_sizes, int n_in,
                              void* d_out, int out_size, void* d_ws, size_t ws_size,
                              hipStream_t stream) {
    const float* x    = (const float*)d_in[0];  // [16,4,64,512]
    const float* filt = (const float*)d_in[1];  // [16,1,14,64,512]
    const float* msk  = (const float*)d_in[2];  // [16,1,64,512]
    float* out = (float*)d_out;
    (void)d_ws; (void)ws_size;

    dim3 grid(WW / TW, HH / TH, BB);   // (16, 8, 16) = 2048 blocks = 8/CU
    dim3 block(256);
    crf_fused<<<grid, block, 0, stream>>>(x, filt, msk, out);
}

// Round 8
// 100.357 us; speedup vs baseline: 1.3118x; 1.0922x over previous
//
#include <hip/hip_runtime.h>

// SqueezeSeg recurrent CRF, MI355X (gfx950). Single-kernel halo-redundant fusion
// (3 iterations in-block, shrinking regions 12x72 -> 10x68 -> 8x64 around 8x64).
// R8 = R4 structure (1 px/slot, short chains) +:
//  - double-buffered class-packed u in LDS: no result registers held across
//    barriers, 1 barrier per step instead of 2;
//  - filt loads batched into a local array ahead of the FMA chain (vmcnt
//    pipelining: globals in flight while LDS reads proceed);
//  - __launch_bounds__(256,4) only (no tighter VGPR clamp -> no spills;
//    R5/R7 lesson).
// g_ang == g_bi (theta=0.9 both) -> ang == bi_ang.
// compat = (1-I)*coef -> out[o] = coef*(sum_c v[c] - v[o]).

#define NCLASS 4
#define HH 64
#define WW 512
#define BB 16
#define TH 8
#define TW 64
#define UR (TH + 6)   // 14 rows : tile + 3 halo each side
#define UC (TW + 12)  // 76 cols : tile + 6 halo each side
#define PLANE (HH * WW)

// exp(-d2 / (2*0.9^2)) for d2 = 1,2,4,5
#define G1 0.53940412f
#define G2 0.29095687f
#define G4 0.08466190f
#define G5 0.04566227f

// neighbor offsets of the 3x5 kernel, center excluded, dz-major (= the
// k-ordering of bilateral_filters), relative offsets in [-1,1]x[-2,2]
#define TAPS                                                                 \
    const int   DZ[14] = {-1,-1,-1,-1,-1,  0, 0, 0, 0,  1, 1, 1, 1, 1};      \
    const int   DA[14] = {-2,-1, 0, 1, 2, -2,-1, 1, 2, -2,-1, 0, 1, 2};      \
    const float GW[14] = {G5,G2,G1,G2,G5, G4,G1,G1,G4, G5,G2,G1,G2,G5};

__device__ __forceinline__ float4 softmax4(float4 v) {
    const float mx = fmaxf(fmaxf(v.x, v.y), fmaxf(v.z, v.w));
    const float e0 = __expf(v.x - mx);
    const float e1 = __expf(v.y - mx);
    const float e2 = __expf(v.z - mx);
    const float e3 = __expf(v.w - mx);
    const float inv = 1.0f / (e0 + e1 + e2 + e3);
    return make_float4(e0 * inv, e1 * inv, e2 * inv, e3 * inv);
}

// MR/MC: halo margin (rows/cols) of the region this step computes.
// Reads u_src, writes softmaxed result to u_dst (FINAL: to global dst).
template <int MR, int MC, bool FINAL>
__device__ __forceinline__ void crf_step(
    const float4 (*__restrict__ u_src)[UC],
    float4 (*__restrict__ u_dst)[UC],
    const float (*__restrict__ m_lds)[UC],
    const float* __restrict__ filt, float* __restrict__ dst,
    int b, int h0, int w0, int tid)
{
    constexpr int RH = TH + 2 * MR;
    constexpr int RW = TW + 2 * MC;
    constexpr int NS = (RH * RW + 255) / 256;
    TAPS

#pragma unroll
    for (int j = 0; j < NS; ++j) {
        const int s = tid + 256 * j;
        if (s < RH * RW) {
            const int lr = s / RW;
            const int lc = s - lr * RW;
            const int gh = h0 + lr - MR;
            const int gw = w0 + lc - MC;
            const int ur = lr + (3 - MR);
            const int uc = lc + (6 - MC);
            const bool in = (gh >= 0) && (gh < HH) && (gw >= 0) && (gw < WW);
            float4 r = make_float4(0.f, 0.f, 0.f, 0.f);
            if (in) {
                // ---- batch all 14 filt loads first (globals in flight) ----
                float F[14];
                const float* fp = filt + ((size_t)b * 14 * HH + gh) * WW + gw;
#pragma unroll
                for (int k = 0; k < 14; ++k)
                    F[k] = fp[(size_t)k * PLANE];

                float a0 = 0.f, a1 = 0.f, a2 = 0.f, a3 = 0.f;
                float c0 = 0.f, c1 = 0.f, c2 = 0.f, c3 = 0.f;
                const float mcen = m_lds[ur][uc];
#pragma unroll
                for (int k = 0; k < 14; ++k) {
                    const float  mn = m_lds[ur + DZ[k]][uc + DA[k]];
                    const float4 u  = u_src[ur + DZ[k]][uc + DA[k]];
                    const float  fm = F[k] * mn;
                    const float  gk = GW[k];
                    a0 = fmaf(gk, u.x, a0);  c0 = fmaf(fm, u.x, c0);
                    a1 = fmaf(gk, u.y, a1);  c1 = fmaf(fm, u.y, c1);
                    a2 = fmaf(gk, u.z, a2);  c2 = fmaf(fm, u.z, c2);
                    a3 = fmaf(gk, u.w, a3);  c3 = fmaf(fm, u.w, c3);
                }
                const float b0 = c0 * mcen * a0;
                const float b1 = c1 * mcen * a1;
                const float b2 = c2 * mcen * a2;
                const float b3 = c3 * mcen * a3;
                const float sa = a0 + a1 + a2 + a3;
                const float sb = b0 + b1 + b2 + b3;
                const float4 ucen = u_src[ur][uc];
                r.x = ucen.x + 0.02f * (sa - a0) + 0.1f * (sb - b0);
                r.y = ucen.y + 0.02f * (sa - a1) + 0.1f * (sb - b1);
                r.z = ucen.z + 0.02f * (sa - a2) + 0.1f * (sb - b2);
                r.w = ucen.w + 0.02f * (sa - a3) + 0.1f * (sb - b3);
            }
            if (FINAL) {
                if (in) {
                    float* o = dst + ((size_t)b * NCLASS * HH + gh) * WW + gw;
                    o[0]         = r.x;
                    o[PLANE]     = r.y;
                    o[2 * PLANE] = r.z;
                    o[3 * PLANE] = r.w;
                }
            } else {
                u_dst[ur][uc] = in ? softmax4(r)
                                   : make_float4(0.f, 0.f, 0.f, 0.f);
            }
        }
    }
    if (!FINAL) __syncthreads();   // u_dst complete before next step reads it
}

__global__ __launch_bounds__(256, 4) void crf_fused(
    const float* __restrict__ xin,   // [B,4,H,W]
    const float* __restrict__ filt,  // [B,1,14,H,W]
    const float* __restrict__ mask,  // [B,1,H,W]
    float* __restrict__ xout)        // [B,4,H,W]
{
    __shared__ float4 uA[UR][UC];    // 17.0 KB
    __shared__ float4 uB[UR][UC];    // 17.0 KB
    __shared__ float  m_lds[UR][UC]; //  4.3 KB  -> 38.3 KB, 4 blocks/CU

    const int b   = blockIdx.z;
    const int h0  = blockIdx.y * TH;
    const int w0  = blockIdx.x * TW;
    const int tid = threadIdx.x;

    // ---- phase 0: softmax(x) + mask over the full 14x76 patch ----
    for (int idx = tid; idx < UR * UC; idx += 256) {
        const int lr = idx / UC;
        const int lc = idx - lr * UC;
        const int gh = h0 + lr - 3;
        const int gw = w0 + lc - 6;
        float4 u = make_float4(0.f, 0.f, 0.f, 0.f);
        float  m = 0.f;
        if (gh >= 0 && gh < HH && gw >= 0 && gw < WW) {
            const float* px = xin + ((size_t)b * NCLASS * HH + gh) * WW + gw;
            u = softmax4(make_float4(px[0], px[PLANE], px[2 * PLANE], px[3 * PLANE]));
            m = mask[((size_t)b * HH + gh) * WW + gw];
        }
        uA[lr][lc]    = u;
        m_lds[lr][lc] = m;
    }
    __syncthreads();

    crf_step<2, 4, false>(uA, uB, m_lds, filt, xout, b, h0, w0, tid);
    crf_step<1, 2, false>(uB, uA, m_lds, filt, xout, b, h0, w0, tid);
    crf_step<0, 0, true >(uA, uB, m_lds, filt, xout, b, h0, w0, tid);
}

extern "C" void kernel_launch(void* const* d_in, const int* in_sizes, int n_in,
                              void* d_out, int out_size, void* d_ws, size_t ws_size,
                              hipStream_t stream) {
    const float* x    = (const float*)d_in[0];  // [16,4,64,512]
    const float* filt = (const float*)d_in[1];  // [16,1,14,64,512]
    const float* msk  = (const float*)d_in[2];  // [16,1,64,512]
    float* out = (float*)d_out;
    (void)d_ws; (void)ws_size;

    dim3 grid(WW / TW, HH / TH, BB);   // (8, 8, 16) = 1024 blocks = 4/CU
    dim3 block(256);
    crf_fused<<<grid, block, 0, stream>>>(x, filt, msk, out);
}